// Round 1
// baseline (536.473 us; speedup 1.0000x reference)
//
#include <hip/hip_runtime.h>

typedef __attribute__((ext_vector_type(8))) short short8;
typedef __attribute__((ext_vector_type(4))) float f32x4;

#define GLOAD16(gp, lp)                                                        \
  __builtin_amdgcn_global_load_lds(                                            \
      (const __attribute__((address_space(1))) void*)(gp),                     \
      (__attribute__((address_space(3))) void*)(lp), 16, 0, 0)

__device__ __forceinline__ unsigned short f2bf(float f) {
  unsigned int u = __builtin_bit_cast(unsigned int, f);
  u += 0x7fffu + ((u >> 16) & 1u);
  return (unsigned short)(u >> 16);
}

// ---------------- f32 -> bf16 convert (vectorized) ----------------
__global__ __launch_bounds__(256) void cvt_f32_bf16(
    const float* __restrict__ src, unsigned short* __restrict__ dst, int n) {
  int i = (blockIdx.x * 256 + threadIdx.x) * 8;
  if (i + 8 <= n) {
    float4 a = *(const float4*)(src + i);
    float4 b = *(const float4*)(src + i + 4);
    short8 r;
    r[0] = (short)f2bf(a.x); r[1] = (short)f2bf(a.y);
    r[2] = (short)f2bf(a.z); r[3] = (short)f2bf(a.w);
    r[4] = (short)f2bf(b.x); r[5] = (short)f2bf(b.y);
    r[6] = (short)f2bf(b.z); r[7] = (short)f2bf(b.w);
    *(short8*)(dst + i) = r;
  }
}

// ---------------- NT GEMM: C[M,N] = A[M,K] * B[N,K]^T ----------------
// 128x128 tile, BK=64, 4 waves (2x2), 16x16x32 bf16 MFMA, global_load_lds(16B)
template <int OUTF32>
__global__ __launch_bounds__(256) void gemm_nt(
    const unsigned short* __restrict__ A, const unsigned short* __restrict__ B,
    void* __restrict__ Cout, const float* __restrict__ bias, int M, int N,
    int K) {
  __shared__ __align__(16) unsigned short As[128][64];
  __shared__ __align__(16) unsigned short Bs[128][64];
  const int tid = threadIdx.x;
  const int wave = tid >> 6, lane = tid & 63;
  const int wr = wave >> 1, wc = wave & 1;
  const int l15 = lane & 15, l16 = lane >> 4;
  const int row0 = blockIdx.x * 128, col0 = blockIdx.y * 128;
  const int srow = lane >> 3;        // 0..7
  const int scol = (lane & 7) * 8;   // 0,8,..,56

  f32x4 acc[4][4] = {};

  for (int k0 = 0; k0 < K; k0 += 64) {
#pragma unroll
    for (int i = 0; i < 4; ++i) {
      const int c = i * 4 + wave;  // chunk 0..15, 8 rows each
      const unsigned short* gpa =
          A + (size_t)(row0 + c * 8 + srow) * K + k0 + scol;
      GLOAD16(gpa, &As[c * 8][0]);
      const unsigned short* gpb =
          B + (size_t)(col0 + c * 8 + srow) * K + k0 + scol;
      GLOAD16(gpb, &Bs[c * 8][0]);
    }
    __syncthreads();
#pragma unroll
    for (int kk = 0; kk < 2; ++kk) {
      short8 a[4], b[4];
#pragma unroll
      for (int m = 0; m < 4; ++m)
        a[m] = *(const short8*)&As[wr * 64 + m * 16 + l15][kk * 32 + l16 * 8];
#pragma unroll
      for (int n = 0; n < 4; ++n)
        b[n] = *(const short8*)&Bs[wc * 64 + n * 16 + l15][kk * 32 + l16 * 8];
#pragma unroll
      for (int m = 0; m < 4; ++m)
#pragma unroll
        for (int n = 0; n < 4; ++n)
          acc[m][n] =
              __builtin_amdgcn_mfma_f32_16x16x32_bf16(a[m], b[n], acc[m][n], 0, 0, 0);
    }
    __syncthreads();
  }

  // epilogue: C row = row0+wr*64+m*16+l16*4+r, col = col0+wc*64+n*16+l15
#pragma unroll
  for (int m = 0; m < 4; ++m) {
    const int row = row0 + wr * 64 + m * 16 + l16 * 4;
#pragma unroll
    for (int n = 0; n < 4; ++n) {
      const int col = col0 + wc * 64 + n * 16 + l15;
      float bv = 0.f;
      if (OUTF32) bv = bias[col];
#pragma unroll
      for (int r = 0; r < 4; ++r) {
        const float v = acc[m][n][r] + bv;
        if (OUTF32)
          ((float*)Cout)[(size_t)(row + r) * N + col] = v;
        else
          ((unsigned short*)Cout)[(size_t)(row + r) * N + col] = f2bf(v);
      }
    }
  }
}

// ---------------- causal flash attention ----------------
// QKV: [8192, 3072] bf16 (Q cols 0..1023, K cols 1024..2047, V cols 2048..3071)
// AO:  [8192, 1024] bf16
// grid (32, 64): x = q-tile (reversed), y = b*16+h. 256 threads = 4 waves,
// each wave owns 16 q-rows; KV tile = 64.
__global__ __launch_bounds__(256) void attn_fwd(
    const unsigned short* __restrict__ QKV, unsigned short* __restrict__ AO) {
  const int S = 2048, LD = 3072, HD = 64;
  const int qt = gridDim.x - 1 - blockIdx.x;  // long blocks launch first
  const int bh = blockIdx.y;
  const int b = bh >> 4, h = bh & 15;
  const int tid = threadIdx.x, wave = tid >> 6, lane = tid & 63;
  const int l15 = lane & 15, l16 = lane >> 4;
  const int q0 = qt * 64;

  __shared__ __align__(16) unsigned short Ks[64][64];
  __shared__ __align__(16) unsigned short VT[64][64];  // V transposed [d][kv]
  __shared__ __align__(16) unsigned short Pl[4][16][64];

  // Q fragments stay in registers for the whole kernel
  const unsigned short* qptr =
      QKV + (size_t)(b * S + q0 + wave * 16 + l15) * LD + h * HD + l16 * 8;
  short8 qf[2];
  qf[0] = *(const short8*)(qptr);
  qf[1] = *(const short8*)(qptr + 32);

  float mrow[4] = {-1e30f, -1e30f, -1e30f, -1e30f};
  float lsum[4] = {0.f, 0.f, 0.f, 0.f};
  f32x4 accO[4] = {};

  const int srow = lane >> 3, scol = (lane & 7) * 8;
  const int qbase = q0 + wave * 16 + l16 * 4;
  const int nkv = qt + 1;

  for (int t = 0; t < nkv; ++t) {
    const int kv0 = t * 64;
    // stage K tile via global_load_lds (8 chunks x 8 rows, 2 per wave)
#pragma unroll
    for (int i = 0; i < 2; ++i) {
      const int c = i * 4 + wave;
      const unsigned short* gp =
          QKV + (size_t)(b * S + kv0 + c * 8 + srow) * LD + 1024 + h * HD + scol;
      GLOAD16(gp, &Ks[c * 8][0]);
    }
    // stage V transposed (coalesced global read, scattered LDS write)
    {
      const int kv = tid >> 2, d0 = (tid & 3) * 16;
      const unsigned short* vp =
          QKV + (size_t)(b * S + kv0 + kv) * LD + 2048 + h * HD + d0;
      short8 v0 = *(const short8*)vp;
      short8 v1 = *(const short8*)(vp + 8);
#pragma unroll
      for (int j = 0; j < 8; ++j) VT[d0 + j][kv] = (unsigned short)v0[j];
#pragma unroll
      for (int j = 0; j < 8; ++j) VT[d0 + 8 + j][kv] = (unsigned short)v1[j];
    }
    __syncthreads();

    // S = Q * K^T  (16 q-rows x 64 kv-cols per wave)
    f32x4 accS[4] = {};
#pragma unroll
    for (int sub = 0; sub < 4; ++sub) {
#pragma unroll
      for (int kk = 0; kk < 2; ++kk) {
        short8 bfrag = *(const short8*)&Ks[sub * 16 + l15][kk * 32 + l16 * 8];
        accS[sub] =
            __builtin_amdgcn_mfma_f32_16x16x32_bf16(qf[kk], bfrag, accS[sub], 0, 0, 0);
      }
    }

    // scale + causal mask (only the diagonal tile needs it)
    const bool need_mask = (kv0 + 63 > qbase);
#pragma unroll
    for (int sub = 0; sub < 4; ++sub)
#pragma unroll
      for (int r = 0; r < 4; ++r) {
        float s = accS[sub][r] * 0.125f;
        if (need_mask && (kv0 + sub * 16 + l15 > qbase + r)) s = -1e30f;
        accS[sub][r] = s;
      }

    // online softmax (row r lives in lanes sharing l16; reduce over 16 lanes)
#pragma unroll
    for (int r = 0; r < 4; ++r) {
      float mx = fmaxf(fmaxf(accS[0][r], accS[1][r]),
                       fmaxf(accS[2][r], accS[3][r]));
      mx = fmaxf(mx, __shfl_xor(mx, 1));
      mx = fmaxf(mx, __shfl_xor(mx, 2));
      mx = fmaxf(mx, __shfl_xor(mx, 4));
      mx = fmaxf(mx, __shfl_xor(mx, 8));
      const float mnew = fmaxf(mrow[r], mx);
      const float alpha = __expf(mrow[r] - mnew);
      mrow[r] = mnew;
      float rs = 0.f;
#pragma unroll
      for (int sub = 0; sub < 4; ++sub) {
        const float pv = __expf(accS[sub][r] - mnew);
        accS[sub][r] = pv;
        rs += pv;
      }
      rs += __shfl_xor(rs, 1);
      rs += __shfl_xor(rs, 2);
      rs += __shfl_xor(rs, 4);
      rs += __shfl_xor(rs, 8);
      lsum[r] = lsum[r] * alpha + rs;
#pragma unroll
      for (int sub = 0; sub < 4; ++sub) accO[sub][r] *= alpha;
    }

    // P -> LDS (C-layout) then back in A-layout for PV
#pragma unroll
    for (int sub = 0; sub < 4; ++sub)
#pragma unroll
      for (int r = 0; r < 4; ++r)
        Pl[wave][l16 * 4 + r][sub * 16 + l15] = f2bf(accS[sub][r]);
    __syncthreads();

#pragma unroll
    for (int kk = 0; kk < 2; ++kk) {
      short8 ap = *(const short8*)&Pl[wave][l15][kk * 32 + l16 * 8];
#pragma unroll
      for (int sub = 0; sub < 4; ++sub) {
        short8 bv = *(const short8*)&VT[sub * 16 + l15][kk * 32 + l16 * 8];
        accO[sub] =
            __builtin_amdgcn_mfma_f32_16x16x32_bf16(ap, bv, accO[sub], 0, 0, 0);
      }
    }
    __syncthreads();  // protect Ks/VT/Pl before next iteration's staging
  }

  // epilogue: O / lsum -> AO[b*S+q][h*64+d]
#pragma unroll
  for (int sub = 0; sub < 4; ++sub)
#pragma unroll
    for (int r = 0; r < 4; ++r) {
      const float o = accO[sub][r] / lsum[r];
      AO[(size_t)(b * S + q0 + wave * 16 + l16 * 4 + r) * 1024 + h * HD +
         sub * 16 + l15] = f2bf(o);
    }
}

// ---------------- launch ----------------
extern "C" void kernel_launch(void* const* d_in, const int* in_sizes, int n_in,
                              void* d_out, int out_size, void* d_ws,
                              size_t ws_size, hipStream_t stream) {
  const float* x = (const float*)d_in[0];
  const float* Wq = (const float*)d_in[1];
  const float* Wk = (const float*)d_in[2];
  const float* Wv = (const float*)d_in[3];
  const float* Wo = (const float*)d_in[4];
  const float* bo = (const float*)d_in[5];

  char* ws = (char*)d_ws;
  unsigned short* xb = (unsigned short*)(ws);                       // 16 MB
  unsigned short* Wqkv = (unsigned short*)(ws + (size_t)(16 << 20)); // 6 MB
  unsigned short* Wob = (unsigned short*)(ws + (size_t)(22 << 20));  // 2 MB
  unsigned short* QKV = (unsigned short*)(ws + (size_t)(24 << 20));  // 48 MB
  unsigned short* AO = (unsigned short*)(ws + (size_t)(72 << 20));   // 16 MB

  const int M = 8192, D = 1024;

  cvt_f32_bf16<<<M * D / 2048, 256, 0, stream>>>(x, xb, M * D);
  cvt_f32_bf16<<<D * D / 2048, 256, 0, stream>>>(Wq, Wqkv, D * D);
  cvt_f32_bf16<<<D * D / 2048, 256, 0, stream>>>(Wk, Wqkv + D * D, D * D);
  cvt_f32_bf16<<<D * D / 2048, 256, 0, stream>>>(Wv, Wqkv + 2 * D * D, D * D);
  cvt_f32_bf16<<<D * D / 2048, 256, 0, stream>>>(Wo, Wob, D * D);

  dim3 g1(M / 128, 3072 / 128);
  gemm_nt<0><<<g1, 256, 0, stream>>>(xb, Wqkv, QKV, nullptr, M, 3072, D);

  dim3 g2(32, 64);
  attn_fwd<<<g2, 256, 0, stream>>>(QKV, AO);

  dim3 g3(M / 128, D / 128);
  gemm_nt<1><<<g3, 256, 0, stream>>>(AO, Wob, d_out, bo, M, D, D);
}

// Round 3
// 380.157 us; speedup vs baseline: 1.4112x; 1.4112x over previous
//
#include <hip/hip_runtime.h>

typedef __attribute__((ext_vector_type(8))) short short8;
typedef __attribute__((ext_vector_type(4))) short bf16x4;
typedef __attribute__((ext_vector_type(4))) float f32x4;

#define GLOAD16(gp, lp)                                                        \
  __builtin_amdgcn_global_load_lds(                                            \
      (const __attribute__((address_space(1))) void*)(gp),                     \
      (__attribute__((address_space(3))) void*)(lp), 16, 0, 0)

__device__ __forceinline__ unsigned short f2bf(float f) {
  unsigned int u = __builtin_bit_cast(unsigned int, f);
  u += 0x7fffu + ((u >> 16) & 1u);
  return (unsigned short)(u >> 16);
}

// ---------------- f32 -> bf16 convert (vectorized) ----------------
__global__ __launch_bounds__(256) void cvt_f32_bf16(
    const float* __restrict__ src, unsigned short* __restrict__ dst, int n) {
  int i = (blockIdx.x * 256 + threadIdx.x) * 8;
  if (i + 8 <= n) {
    float4 a = *(const float4*)(src + i);
    float4 b = *(const float4*)(src + i + 4);
    short8 r;
    r[0] = (short)f2bf(a.x); r[1] = (short)f2bf(a.y);
    r[2] = (short)f2bf(a.z); r[3] = (short)f2bf(a.w);
    r[4] = (short)f2bf(b.x); r[5] = (short)f2bf(b.y);
    r[6] = (short)f2bf(b.z); r[7] = (short)f2bf(b.w);
    *(short8*)(dst + i) = r;
  }
}

// ---------------- NT GEMM: C[M,N] = A[M,K] * B[N,K]^T ----------------
// 128x128 tile, BK=64, 4 waves (2x2), 16x16x32 bf16 MFMA, global_load_lds(16B)
template <int OUTF32>
__global__ __launch_bounds__(256) void gemm_nt(
    const unsigned short* __restrict__ A, const unsigned short* __restrict__ B,
    void* __restrict__ Cout, const float* __restrict__ bias, int M, int N,
    int K) {
  __shared__ __align__(16) unsigned short As[128][64];
  __shared__ __align__(16) unsigned short Bs[128][64];
  const int tid = threadIdx.x;
  const int wave = tid >> 6, lane = tid & 63;
  const int wr = wave >> 1, wc = wave & 1;
  const int l15 = lane & 15, l16 = lane >> 4;
  const int row0 = blockIdx.x * 128, col0 = blockIdx.y * 128;
  const int srow = lane >> 3;        // 0..7
  const int scol = (lane & 7) * 8;   // 0,8,..,56

  f32x4 acc[4][4] = {};

  for (int k0 = 0; k0 < K; k0 += 64) {
#pragma unroll
    for (int i = 0; i < 4; ++i) {
      const int c = i * 4 + wave;  // chunk 0..15, 8 rows each
      const unsigned short* gpa =
          A + (size_t)(row0 + c * 8 + srow) * K + k0 + scol;
      GLOAD16(gpa, &As[c * 8][0]);
      const unsigned short* gpb =
          B + (size_t)(col0 + c * 8 + srow) * K + k0 + scol;
      GLOAD16(gpb, &Bs[c * 8][0]);
    }
    __syncthreads();
#pragma unroll
    for (int kk = 0; kk < 2; ++kk) {
      short8 a[4], b[4];
#pragma unroll
      for (int m = 0; m < 4; ++m)
        a[m] = *(const short8*)&As[wr * 64 + m * 16 + l15][kk * 32 + l16 * 8];
#pragma unroll
      for (int n = 0; n < 4; ++n)
        b[n] = *(const short8*)&Bs[wc * 64 + n * 16 + l15][kk * 32 + l16 * 8];
#pragma unroll
      for (int m = 0; m < 4; ++m)
#pragma unroll
        for (int n = 0; n < 4; ++n)
          acc[m][n] =
              __builtin_amdgcn_mfma_f32_16x16x32_bf16(a[m], b[n], acc[m][n], 0, 0, 0);
    }
    __syncthreads();
  }

#pragma unroll
  for (int m = 0; m < 4; ++m) {
    const int row = row0 + wr * 64 + m * 16 + l16 * 4;
#pragma unroll
    for (int n = 0; n < 4; ++n) {
      const int col = col0 + wc * 64 + n * 16 + l15;
      float bv = 0.f;
      if (OUTF32) bv = bias[col];
#pragma unroll
      for (int r = 0; r < 4; ++r) {
        const float v = acc[m][n][r] + bv;
        if (OUTF32)
          ((float*)Cout)[(size_t)(row + r) * N + col] = v;
        else
          ((unsigned short*)Cout)[(size_t)(row + r) * N + col] = f2bf(v);
      }
    }
  }
}

// ---------------- causal flash attention (swapped-QK, swizzled LDS) --------
// QKV: [8192, 3072] bf16 (Q 0..1023, K 1024..2047, V 2048..3071)
// AO:  [8192, 1024] bf16
// grid (32, 64): x = q-tile (reversed), y = b*16+h. 4 waves x 16 q-rows.
// Swapped QK^T: lane holds S[kv = sub*16+l16*4+r][q = l15] -> per-lane softmax.
// All LDS tiles (128B rows) XOR-swizzled: byte ^= ((row&7)<<4).
// Ks staged via global_load_lds with PRE-SWIZZLED global source (rule #21).
// Double-buffered Ks/VT, one barrier per KV tile.
__global__ __launch_bounds__(256) void attn_fwd(
    const unsigned short* __restrict__ QKV, unsigned short* __restrict__ AO) {
  const int S = 2048, LD = 3072;
  const int qt = gridDim.x - 1 - blockIdx.x;  // long blocks launch first
  const int bh = blockIdx.y, b = bh >> 4, h = bh & 15;
  const int tid = threadIdx.x, wave = tid >> 6, lane = tid & 63;
  const int l15 = lane & 15, l16 = lane >> 4;
  const int q0 = qt * 64;

  __shared__ __align__(16) char KsB[2][64 * 128];
  __shared__ __align__(16) char VTB[2][64 * 128];  // V^T: [d][kv]
  __shared__ __align__(16) char PlB[4][16 * 128];  // per-wave P [q][kv]

  // Q fragment (B operand of swapped QK): rows q0 + wave*16 + l15
  const unsigned short* qptr =
      QKV + (size_t)(b * S + q0 + wave * 16 + l15) * LD + h * 64 + l16 * 8;
  short8 qf[2];
  qf[0] = *(const short8*)(qptr);
  qf[1] = *(const short8*)(qptr + 32);

  // K staging: pre-swizzled global column so linear gload_lds dest lands
  // swizzled content. lane covers row c*8 + (lane>>3), 16B slot (lane&7).
  const int krow = lane >> 3;
  const int kcol = (((lane & 7) ^ (lane >> 3)) & 7) * 8;
  // V staging: kv pair p = tid&31, d block d0 = (tid>>5)*8
  const int vp_ = tid & 31, vd0 = (tid >> 5) * 8;

  float mrow = -1e30f, lsum = 0.f;
  f32x4 accO[4] = {};
  const int nkv = qt + 1;
  const float SC2 = 0.125f * 1.44269504088896340736f;  // scale * log2(e)

  // ---- prologue: stage tile 0 into buffer 0
  {
#pragma unroll
    for (int i = 0; i < 2; ++i) {
      const int c = i * 4 + wave;
      const unsigned short* gp =
          QKV + (size_t)(b * S + c * 8 + krow) * LD + 1024 + h * 64 + kcol;
      GLOAD16(gp, KsB[0] + c * 1024);
    }
    const unsigned short* vp =
        QKV + (size_t)(b * S + 2 * vp_) * LD + 2048 + h * 64 + vd0;
    short8 va = *(const short8*)vp;
    short8 vb = *(const short8*)(vp + LD);
#pragma unroll
    for (int j = 0; j < 8; ++j) {
      unsigned int val =
          (unsigned short)va[j] | ((unsigned int)(unsigned short)vb[j] << 16);
      *(unsigned int*)(VTB[0] + (((vd0 + j) * 128 + 4 * vp_) ^ (j << 4))) = val;
    }
  }
  __syncthreads();

  for (int t = 0; t < nkv; ++t) {
    const int cur = t & 1, kv0 = t * 64;

    // --- swapped QK^T: acc[sub][r] = S[kv0+sub*16+l16*4+r][q0+wave*16+l15]
    f32x4 accS[4] = {};
#pragma unroll
    for (int sub = 0; sub < 4; ++sub) {
      const int rw = sub * 16 + l15;
#pragma unroll
      for (int kk = 0; kk < 2; ++kk) {
        short8 kf = *(const short8*)(KsB[cur] + rw * 128 +
                                     ((kk * 64 + l16 * 16) ^ ((l15 & 7) << 4)));
        accS[sub] =
            __builtin_amdgcn_mfma_f32_16x16x32_bf16(kf, qf[kk], accS[sub], 0, 0, 0);
      }
    }

    // --- prefetch next tile (issue loads early; hide under softmax)
    short8 va, vb;
    const bool pre = (t + 1 < nkv);
    if (pre) {
      const int kvn = kv0 + 64;
#pragma unroll
      for (int i = 0; i < 2; ++i) {
        const int c = i * 4 + wave;
        const unsigned short* gp =
            QKV + (size_t)(b * S + kvn + c * 8 + krow) * LD + 1024 + h * 64 + kcol;
        GLOAD16(gp, KsB[cur ^ 1] + c * 1024);
      }
      const unsigned short* vp =
          QKV + (size_t)(b * S + kvn + 2 * vp_) * LD + 2048 + h * 64 + vd0;
      va = *(const short8*)vp;
      vb = *(const short8*)(vp + LD);
    }

    // --- softmax (exp2 domain), per lane q = q0 + wave*16 + l15
    const bool nm = (kv0 + 63 > q0 + wave * 16);
    float mx = -1e30f;
#pragma unroll
    for (int sub = 0; sub < 4; ++sub)
#pragma unroll
      for (int r = 0; r < 4; ++r) {
        float s = accS[sub][r] * SC2;
        if (nm && (kv0 + sub * 16 + l16 * 4 + r > q0 + wave * 16 + l15))
          s = -1e30f;
        accS[sub][r] = s;
        mx = fmaxf(mx, s);
      }
    mx = fmaxf(mx, __shfl_xor(mx, 16));
    mx = fmaxf(mx, __shfl_xor(mx, 32));
    const float mnew = fmaxf(mrow, mx);
    const float alpha = exp2f(mrow - mnew);
    mrow = mnew;
    float rs = 0.f;
#pragma unroll
    for (int sub = 0; sub < 4; ++sub)
#pragma unroll
      for (int r = 0; r < 4; ++r) {
        const float pv = exp2f(accS[sub][r] - mnew);
        accS[sub][r] = pv;
        rs += pv;
      }
    rs += __shfl_xor(rs, 16);
    rs += __shfl_xor(rs, 32);
    lsum = lsum * alpha + rs;

    // --- write next V^T (vmcnt wait on va/vb inserted by compiler)
    if (pre) {
#pragma unroll
      for (int j = 0; j < 8; ++j) {
        unsigned int val =
            (unsigned short)va[j] | ((unsigned int)(unsigned short)vb[j] << 16);
        *(unsigned int*)(VTB[cur ^ 1] + (((vd0 + j) * 128 + 4 * vp_) ^ (j << 4))) =
            val;
      }
    }

    // --- P -> Pl (wave-private; 4x ds_write_b64, r-values contiguous in kv)
#pragma unroll
    for (int sub = 0; sub < 4; ++sub) {
      bf16x4 pk;
#pragma unroll
      for (int r = 0; r < 4; ++r) pk[r] = (short)f2bf(accS[sub][r]);
      *(bf16x4*)(PlB[wave] +
                 ((l15 * 128 + sub * 32 + l16 * 8) ^ ((l15 & 7) << 4))) = pk;
    }

    // --- rescale accO by alpha(q), q = l16*4+r lives in lane l16*4+r
    float al[4];
#pragma unroll
    for (int r = 0; r < 4; ++r) al[r] = __shfl(alpha, l16 * 4 + r);
#pragma unroll
    for (int sd = 0; sd < 4; ++sd)
#pragma unroll
      for (int r = 0; r < 4; ++r) accO[sd][r] *= al[r];

    // --- PV: O[q][d] += P[q][kv] * VT[d][kv]^T
#pragma unroll
    for (int kk = 0; kk < 2; ++kk) {
      short8 pf = *(const short8*)(PlB[wave] + ((l15 * 128 + kk * 64 + l16 * 16) ^
                                               ((l15 & 7) << 4)));
#pragma unroll
      for (int sd = 0; sd < 4; ++sd) {
        short8 vf = *(const short8*)(VTB[cur] + (sd * 16 + l15) * 128 +
                                     ((kk * 64 + l16 * 16) ^ ((l15 & 7) << 4)));
        accO[sd] =
            __builtin_amdgcn_mfma_f32_16x16x32_bf16(pf, vf, accO[sd], 0, 0, 0);
      }
    }
    __syncthreads();
  }

  // --- epilogue: O[q][d] / lsum(q)
  float ls[4];
#pragma unroll
  for (int r = 0; r < 4; ++r) ls[r] = __shfl(lsum, l16 * 4 + r);
#pragma unroll
  for (int sd = 0; sd < 4; ++sd)
#pragma unroll
    for (int r = 0; r < 4; ++r) {
      AO[(size_t)(b * S + q0 + wave * 16 + l16 * 4 + r) * 1024 + h * 64 +
         sd * 16 + l15] = f2bf(accO[sd][r] / ls[r]);
    }
}

// ---------------- launch ----------------
extern "C" void kernel_launch(void* const* d_in, const int* in_sizes, int n_in,
                              void* d_out, int out_size, void* d_ws,
                              size_t ws_size, hipStream_t stream) {
  const float* x = (const float*)d_in[0];
  const float* Wq = (const float*)d_in[1];
  const float* Wk = (const float*)d_in[2];
  const float* Wv = (const float*)d_in[3];
  const float* Wo = (const float*)d_in[4];
  const float* bo = (const float*)d_in[5];

  char* ws = (char*)d_ws;
  unsigned short* xb = (unsigned short*)(ws);                        // 16 MB
  unsigned short* Wqkv = (unsigned short*)(ws + (size_t)(16 << 20)); // 6 MB
  unsigned short* Wob = (unsigned short*)(ws + (size_t)(22 << 20));  // 2 MB
  unsigned short* QKV = (unsigned short*)(ws + (size_t)(24 << 20));  // 48 MB
  unsigned short* AO = (unsigned short*)(ws + (size_t)(72 << 20));   // 16 MB

  const int M = 8192, D = 1024;

  cvt_f32_bf16<<<M * D / 2048, 256, 0, stream>>>(x, xb, M * D);
  cvt_f32_bf16<<<D * D / 2048, 256, 0, stream>>>(Wq, Wqkv, D * D);
  cvt_f32_bf16<<<D * D / 2048, 256, 0, stream>>>(Wk, Wqkv + D * D, D * D);
  cvt_f32_bf16<<<D * D / 2048, 256, 0, stream>>>(Wv, Wqkv + 2 * D * D, D * D);
  cvt_f32_bf16<<<D * D / 2048, 256, 0, stream>>>(Wo, Wob, D * D);

  dim3 g1(M / 128, 3072 / 128);
  gemm_nt<0><<<g1, 256, 0, stream>>>(xb, Wqkv, QKV, nullptr, M, 3072, D);

  dim3 g2(32, 64);
  attn_fwd<<<g2, 256, 0, stream>>>(QKV, AO);

  dim3 g3(M / 128, D / 128);
  gemm_nt<1><<<g3, 256, 0, stream>>>(AO, Wob, d_out, bo, M, D, D);
}

// Round 4
// 349.243 us; speedup vs baseline: 1.5361x; 1.0885x over previous
//
#include <hip/hip_runtime.h>

typedef __attribute__((ext_vector_type(8))) short short8;
typedef __attribute__((ext_vector_type(4))) float f32x4;

#define GLOAD16(gp, lp)                                                        \
  __builtin_amdgcn_global_load_lds(                                            \
      (const __attribute__((address_space(1))) void*)(gp),                     \
      (__attribute__((address_space(3))) void*)(lp), 16, 0, 0)

__device__ __forceinline__ unsigned short f2bf(float f) {
  unsigned int u = __builtin_bit_cast(unsigned int, f);
  u += 0x7fffu + ((u >> 16) & 1u);
  return (unsigned short)(u >> 16);
}

// ---------------- f32 -> bf16 convert (vectorized, optional scale) ---------
__global__ __launch_bounds__(256) void cvt_f32_bf16(
    const float* __restrict__ src, unsigned short* __restrict__ dst, int n,
    float scale) {
  int i = (blockIdx.x * 256 + threadIdx.x) * 8;
  if (i + 8 <= n) {
    float4 a = *(const float4*)(src + i);
    float4 b = *(const float4*)(src + i + 4);
    short8 r;
    r[0] = (short)f2bf(a.x * scale); r[1] = (short)f2bf(a.y * scale);
    r[2] = (short)f2bf(a.z * scale); r[3] = (short)f2bf(a.w * scale);
    r[4] = (short)f2bf(b.x * scale); r[5] = (short)f2bf(b.y * scale);
    r[6] = (short)f2bf(b.z * scale); r[7] = (short)f2bf(b.w * scale);
    *(short8*)(dst + i) = r;
  }
}

// ---------------- NT GEMM: C[M,N] = A[M,K] * B[N,K]^T ----------------
template <int OUTF32>
__global__ __launch_bounds__(256) void gemm_nt(
    const unsigned short* __restrict__ A, const unsigned short* __restrict__ B,
    void* __restrict__ Cout, const float* __restrict__ bias, int M, int N,
    int K) {
  __shared__ __align__(16) unsigned short As[128][64];
  __shared__ __align__(16) unsigned short Bs[128][64];
  const int tid = threadIdx.x;
  const int wave = tid >> 6, lane = tid & 63;
  const int wr = wave >> 1, wc = wave & 1;
  const int l15 = lane & 15, l16 = lane >> 4;
  const int row0 = blockIdx.x * 128, col0 = blockIdx.y * 128;
  const int srow = lane >> 3;
  const int scol = (lane & 7) * 8;

  f32x4 acc[4][4] = {};

  for (int k0 = 0; k0 < K; k0 += 64) {
#pragma unroll
    for (int i = 0; i < 4; ++i) {
      const int c = i * 4 + wave;
      const unsigned short* gpa =
          A + (size_t)(row0 + c * 8 + srow) * K + k0 + scol;
      GLOAD16(gpa, &As[c * 8][0]);
      const unsigned short* gpb =
          B + (size_t)(col0 + c * 8 + srow) * K + k0 + scol;
      GLOAD16(gpb, &Bs[c * 8][0]);
    }
    __syncthreads();
#pragma unroll
    for (int kk = 0; kk < 2; ++kk) {
      short8 a[4], b[4];
#pragma unroll
      for (int m = 0; m < 4; ++m)
        a[m] = *(const short8*)&As[wr * 64 + m * 16 + l15][kk * 32 + l16 * 8];
#pragma unroll
      for (int n = 0; n < 4; ++n)
        b[n] = *(const short8*)&Bs[wc * 64 + n * 16 + l15][kk * 32 + l16 * 8];
#pragma unroll
      for (int m = 0; m < 4; ++m)
#pragma unroll
        for (int n = 0; n < 4; ++n)
          acc[m][n] =
              __builtin_amdgcn_mfma_f32_16x16x32_bf16(a[m], b[n], acc[m][n], 0, 0, 0);
    }
    __syncthreads();
  }

#pragma unroll
  for (int m = 0; m < 4; ++m) {
    const int row = row0 + wr * 64 + m * 16 + l16 * 4;
#pragma unroll
    for (int n = 0; n < 4; ++n) {
      const int col = col0 + wc * 64 + n * 16 + l15;
      float bv = 0.f;
      if (OUTF32) bv = bias[col];
#pragma unroll
      for (int r = 0; r < 4; ++r) {
        const float v = acc[m][n][r] + bv;
        if (OUTF32)
          ((float*)Cout)[(size_t)(row + r) * N + col] = v;
        else
          ((unsigned short*)Cout)[(size_t)(row + r) * N + col] = f2bf(v);
      }
    }
  }
}

// ---------------- causal flash attention ----------------
// Q pre-scaled by 0.125*log2e (folded into W_q) -> scores in exp2 domain.
// Swapped QK^T (lane holds one q-row), T2 XOR-swizzled LDS, 1 barrier/tile,
// uniform-branch causal mask (diagonal tile only), defer-max THR=8,
// v_cvt_pk_bf16_f32 P-pack, v_perm V-transpose pack.
__global__ __launch_bounds__(256) void attn_fwd(
    const unsigned short* __restrict__ QKV, unsigned short* __restrict__ AO) {
  const int S = 2048, LD = 3072;
  const int qt = gridDim.x - 1 - blockIdx.x;
  const int bh = blockIdx.y, b = bh >> 4, h = bh & 15;
  const int tid = threadIdx.x, wave = tid >> 6, lane = tid & 63;
  const int l15 = lane & 15, l16 = lane >> 4;
  const int q0 = qt * 64;

  __shared__ __align__(16) char KsB[2][64 * 128];
  __shared__ __align__(16) char VTB[2][64 * 128];
  __shared__ __align__(16) char PlB[4][16 * 128];

  const unsigned short* qptr =
      QKV + (size_t)(b * S + q0 + wave * 16 + l15) * LD + h * 64 + l16 * 8;
  short8 qf[2];
  qf[0] = *(const short8*)(qptr);
  qf[1] = *(const short8*)(qptr + 32);

  const int krow = lane >> 3;
  const int kcol = (((lane & 7) ^ (lane >> 3)) & 7) * 8;
  const int vp_ = tid & 31, vd0 = (tid >> 5) * 8;

  float mrow = -1e30f, lsum = 0.f;
  f32x4 accO[4] = {};
  const int nkv = qt + 1;

  // ---- prologue: stage tile 0
  {
#pragma unroll
    for (int i = 0; i < 2; ++i) {
      const int c = i * 4 + wave;
      const unsigned short* gp =
          QKV + (size_t)(b * S + c * 8 + krow) * LD + 1024 + h * 64 + kcol;
      GLOAD16(gp, KsB[0] + c * 1024);
    }
    const unsigned short* vp =
        QKV + (size_t)(b * S + 2 * vp_) * LD + 2048 + h * 64 + vd0;
    short8 va = *(const short8*)vp;
    short8 vb = *(const short8*)(vp + LD);
    uint4 vaw = __builtin_bit_cast(uint4, va);
    uint4 vbw = __builtin_bit_cast(uint4, vb);
    const unsigned int aw[4] = {vaw.x, vaw.y, vaw.z, vaw.w};
    const unsigned int bw[4] = {vbw.x, vbw.y, vbw.z, vbw.w};
#pragma unroll
    for (int w = 0; w < 4; ++w) {
      unsigned int e = __builtin_amdgcn_perm(bw[w], aw[w], 0x05040100u);
      unsigned int o = __builtin_amdgcn_perm(bw[w], aw[w], 0x07060302u);
      *(unsigned int*)(VTB[0] + (((vd0 + 2 * w) * 128 + 4 * vp_) ^ ((2 * w) << 4))) = e;
      *(unsigned int*)(VTB[0] + (((vd0 + 2 * w + 1) * 128 + 4 * vp_) ^ ((2 * w + 1) << 4))) = o;
    }
  }
  __syncthreads();

  for (int t = 0; t < nkv; ++t) {
    const int cur = t & 1, kv0 = t * 64;

    // --- swapped QK^T (Q pre-scaled; result already in exp2 domain)
    f32x4 accS[4] = {};
#pragma unroll
    for (int sub = 0; sub < 4; ++sub) {
      const int rw = sub * 16 + l15;
#pragma unroll
      for (int kk = 0; kk < 2; ++kk) {
        short8 kf = *(const short8*)(KsB[cur] + rw * 128 +
                                     ((kk * 64 + l16 * 16) ^ ((l15 & 7) << 4)));
        accS[sub] =
            __builtin_amdgcn_mfma_f32_16x16x32_bf16(kf, qf[kk], accS[sub], 0, 0, 0);
      }
    }

    // --- prefetch next tile
    short8 va, vb;
    const bool pre = (t + 1 < nkv);
    if (pre) {
      const int kvn = kv0 + 64;
#pragma unroll
      for (int i = 0; i < 2; ++i) {
        const int c = i * 4 + wave;
        const unsigned short* gp =
            QKV + (size_t)(b * S + kvn + c * 8 + krow) * LD + 1024 + h * 64 + kcol;
        GLOAD16(gp, KsB[cur ^ 1] + c * 1024);
      }
      const unsigned short* vp =
          QKV + (size_t)(b * S + kvn + 2 * vp_) * LD + 2048 + h * 64 + vd0;
      va = *(const short8*)vp;
      vb = *(const short8*)(vp + LD);
    }

    // --- row max (mask only on the diagonal tile; wave-uniform branch)
    const bool nm = (kv0 + 63 > q0 + wave * 16);
    float mx = -1e30f;
    if (nm) {
      const int qabs = q0 + wave * 16 + l15;
#pragma unroll
      for (int sub = 0; sub < 4; ++sub)
#pragma unroll
        for (int r = 0; r < 4; ++r) {
          float s = accS[sub][r];
          if (kv0 + sub * 16 + l16 * 4 + r > qabs) s = -1e30f;
          accS[sub][r] = s;
          mx = fmaxf(mx, s);
        }
    } else {
#pragma unroll
      for (int sub = 0; sub < 4; ++sub)
#pragma unroll
        for (int r = 0; r < 4; ++r) mx = fmaxf(mx, accS[sub][r]);
    }
    mx = fmaxf(mx, __shfl_xor(mx, 16));
    mx = fmaxf(mx, __shfl_xor(mx, 32));

    // --- defer-max (T13): rescale only when max grew past THR=8 (log2)
    if (__any(mx > mrow + 8.0f)) {
      const float mnew = fmaxf(mrow, mx);
      const float alpha = exp2f(mrow - mnew);
      mrow = mnew;
      lsum *= alpha;
      float al[4];
#pragma unroll
      for (int r = 0; r < 4; ++r) al[r] = __shfl(alpha, l16 * 4 + r);
#pragma unroll
      for (int sd = 0; sd < 4; ++sd)
#pragma unroll
        for (int r = 0; r < 4; ++r) accO[sd][r] *= al[r];
    }

    // --- P = exp2(S - mrow), pack via v_cvt_pk_bf16_f32, sum
    float rs = 0.f;
#pragma unroll
    for (int sub = 0; sub < 4; ++sub) {
      float p0 = exp2f(accS[sub][0] - mrow);
      float p1 = exp2f(accS[sub][1] - mrow);
      float p2 = exp2f(accS[sub][2] - mrow);
      float p3 = exp2f(accS[sub][3] - mrow);
      rs += (p0 + p1) + (p2 + p3);
      unsigned int pk01, pk23;
      asm("v_cvt_pk_bf16_f32 %0, %1, %2" : "=v"(pk01) : "v"(p0), "v"(p1));
      asm("v_cvt_pk_bf16_f32 %0, %1, %2" : "=v"(pk23) : "v"(p2), "v"(p3));
      uint2 pw = {pk01, pk23};
      *(uint2*)(PlB[wave] +
                ((l15 * 128 + sub * 32 + l16 * 8) ^ ((l15 & 7) << 4))) = pw;
    }
    rs += __shfl_xor(rs, 16);
    rs += __shfl_xor(rs, 32);
    lsum += rs;

    // --- write next V^T (v_perm pack)
    if (pre) {
      uint4 vaw = __builtin_bit_cast(uint4, va);
      uint4 vbw = __builtin_bit_cast(uint4, vb);
      const unsigned int aw[4] = {vaw.x, vaw.y, vaw.z, vaw.w};
      const unsigned int bw[4] = {vbw.x, vbw.y, vbw.z, vbw.w};
#pragma unroll
      for (int w = 0; w < 4; ++w) {
        unsigned int e = __builtin_amdgcn_perm(bw[w], aw[w], 0x05040100u);
        unsigned int o = __builtin_amdgcn_perm(bw[w], aw[w], 0x07060302u);
        *(unsigned int*)(VTB[cur ^ 1] +
                         (((vd0 + 2 * w) * 128 + 4 * vp_) ^ ((2 * w) << 4))) = e;
        *(unsigned int*)(VTB[cur ^ 1] +
                         (((vd0 + 2 * w + 1) * 128 + 4 * vp_) ^ ((2 * w + 1) << 4))) = o;
      }
    }

    // --- PV: O[q][d] += P[q][kv] * VT[d][kv]^T
#pragma unroll
    for (int kk = 0; kk < 2; ++kk) {
      short8 pf = *(const short8*)(PlB[wave] + ((l15 * 128 + kk * 64 + l16 * 16) ^
                                               ((l15 & 7) << 4)));
#pragma unroll
      for (int sd = 0; sd < 4; ++sd) {
        short8 vf = *(const short8*)(VTB[cur] + (sd * 16 + l15) * 128 +
                                     ((kk * 64 + l16 * 16) ^ ((l15 & 7) << 4)));
        accO[sd] =
            __builtin_amdgcn_mfma_f32_16x16x32_bf16(pf, vf, accO[sd], 0, 0, 0);
      }
    }
    __syncthreads();
  }

  // --- epilogue
  float ls[4];
#pragma unroll
  for (int r = 0; r < 4; ++r) ls[r] = __shfl(lsum, l16 * 4 + r);
#pragma unroll
  for (int sd = 0; sd < 4; ++sd)
#pragma unroll
    for (int r = 0; r < 4; ++r) {
      AO[(size_t)(b * S + q0 + wave * 16 + l16 * 4 + r) * 1024 + h * 64 +
         sd * 16 + l15] = f2bf(accO[sd][r] / ls[r]);
    }
}

// ---------------- launch ----------------
extern "C" void kernel_launch(void* const* d_in, const int* in_sizes, int n_in,
                              void* d_out, int out_size, void* d_ws,
                              size_t ws_size, hipStream_t stream) {
  const float* x = (const float*)d_in[0];
  const float* Wq = (const float*)d_in[1];
  const float* Wk = (const float*)d_in[2];
  const float* Wv = (const float*)d_in[3];
  const float* Wo = (const float*)d_in[4];
  const float* bo = (const float*)d_in[5];

  char* ws = (char*)d_ws;
  unsigned short* xb = (unsigned short*)(ws);                        // 16 MB
  unsigned short* Wqkv = (unsigned short*)(ws + (size_t)(16 << 20)); // 6 MB
  unsigned short* Wob = (unsigned short*)(ws + (size_t)(22 << 20));  // 2 MB
  unsigned short* QKV = (unsigned short*)(ws + (size_t)(24 << 20));  // 48 MB
  unsigned short* AO = (unsigned short*)(ws + (size_t)(72 << 20));   // 16 MB

  const int M = 8192, D = 1024;
  const float QSCALE = 0.125f * 1.44269504088896340736f;  // 1/sqrt(dk)*log2(e)

  cvt_f32_bf16<<<M * D / 2048, 256, 0, stream>>>(x, xb, M * D, 1.0f);
  cvt_f32_bf16<<<D * D / 2048, 256, 0, stream>>>(Wq, Wqkv, D * D, QSCALE);
  cvt_f32_bf16<<<D * D / 2048, 256, 0, stream>>>(Wk, Wqkv + D * D, D * D, 1.0f);
  cvt_f32_bf16<<<D * D / 2048, 256, 0, stream>>>(Wv, Wqkv + 2 * D * D, D * D, 1.0f);
  cvt_f32_bf16<<<D * D / 2048, 256, 0, stream>>>(Wo, Wob, D * D, 1.0f);

  dim3 g1(M / 128, 3072 / 128);
  gemm_nt<0><<<g1, 256, 0, stream>>>(xb, Wqkv, QKV, nullptr, M, 3072, D);

  dim3 g2(32, 64);
  attn_fwd<<<g2, 256, 0, stream>>>(QKV, AO);

  dim3 g3(M / 128, D / 128);
  gemm_nt<1><<<g3, 256, 0, stream>>>(AO, Wob, d_out, bo, M, D, D);
}